// Round 8
// baseline (12547.967 us; speedup 1.0000x reference)
//
#include <hip/hip_runtime.h>
#include <math.h>

#define NP 16384
#define SP 4096
#define CINCH 32
#define CO 64
#define KK 16

// ---------------- helpers ----------------
__device__ __forceinline__ float waveGemm64(float xv, const float* __restrict__ wl, int c) {
  float a0=0.f,a1=0.f,a2=0.f,a3=0.f;
  #pragma unroll
  for (int k=0;k<64;k+=4){
    a0 = fmaf(__shfl(xv,k  ), wl[(k  )*CO+c], a0);
    a1 = fmaf(__shfl(xv,k+1), wl[(k+1)*CO+c], a1);
    a2 = fmaf(__shfl(xv,k+2), wl[(k+2)*CO+c], a2);
    a3 = fmaf(__shfl(xv,k+3), wl[(k+3)*CO+c], a3);
  }
  return (a0+a1)+(a2+a3);
}

// ---------------- pts4: pack xyz + |p|^2 ----------------
__global__ __launch_bounds__(256) void k_pts4(const float* __restrict__ pts, float4* __restrict__ pts4) {
  int i = blockIdx.x*256 + threadIdx.x;
  float x = pts[3*i], y = pts[3*i+1], z = pts[3*i+2];
  pts4[i] = make_float4(x,y,z, x*x + y*y + z*z);
}

// ---------------- QKV projections ----------------
__global__ __launch_bounds__(256) void k_qkv(const float* __restrict__ feat,
    const float* __restrict__ Wq, const float* __restrict__ Wk, const float* __restrict__ Wv,
    float* __restrict__ fq, float* __restrict__ fk, float* __restrict__ fv) {
  int r = threadIdx.x >> 6, c = threadIdx.x & 63;
  int row = blockIdx.x*4 + r;
  const float* f = feat + row*CINCH;
  float aq=0.f, ak=0.f, av=0.f;
  #pragma unroll
  for (int k=0;k<CINCH;k++){
    float fe = f[k];
    aq = fmaf(fe, Wq[k*CO+c], aq);
    ak = fmaf(fe, Wk[k*CO+c], ak);
    av = fmaf(fe, Wv[k*CO+c], av);
  }
  fq[row*CO+c]=aq; fk[row*CO+c]=ak; fv[row*CO+c]=av;
}

// ---------------- KNN16 partial: per-part register top-16 (sorted-shift) ----------------
#define KTS 2048
__global__ __launch_bounds__(256,4) void k_knn16p(const float4* __restrict__ qp,
    const float4* __restrict__ cp, int clen,
    float* __restrict__ psv, int* __restrict__ psi) {
  __shared__ float4 tile[KTS];
  int q = blockIdx.x*256 + threadIdx.x;
  int part = blockIdx.y;
  int nspl = gridDim.y;
  int c0 = part*clen;
  float4 tq = qp[q];
  float qx=tq.x, qy=tq.y, qz=tq.z;
  float v[KK]; int id[KK];
  #pragma unroll
  for (int k=0;k<KK;k++){ v[k]=3.4e38f; id[k]=0x7fffffff; }
  for (int base=c0; base<c0+clen; base+=KTS){
    __syncthreads();
    for (int tt=threadIdx.x;tt<KTS;tt+=256) tile[tt]=cp[base+tt];
    __syncthreads();
    for (int j=0;j<KTS;j++){
      float4 cpt=tile[j];
      float dot = qx*cpt.x + qy*cpt.y + qz*cpt.z;
      float s = fmaf(-2.f,dot,cpt.w);
      if (s < v[KK-1]) {             // strict: equal value stays out (earlier index wins)
        int gj = base+j;
        #pragma unroll
        for (int k=KK-1;k>=1;--k){
          bool sh = s < v[k-1];
          bool pl = s < v[k];        // old v[k]
          float nv = sh ? v[k-1] : (pl ? s  : v[k]);
          int   ni = sh ? id[k-1] : (pl ? gj : id[k]);
          v[k]=nv; id[k]=ni;
        }
        if (s < v[0]){ v[0]=s; id[0]=gj; }
      }
    }
  }
  size_t o = ((size_t)q*nspl + part)*KK;
  #pragma unroll
  for (int k=0;k<KK;k++){ psv[o+k]=v[k]; psi[o+k]=id[k]; }
}

// ---------------- merge NS sorted 16-lists -> top 16 (lexicographic (v,idx)) ----------------
template<int NS>
__global__ __launch_bounds__(256,4) void k_merge(const float* __restrict__ psv,
    const int* __restrict__ psi, int* __restrict__ oidx) {
  int q = blockIdx.x*256 + threadIdx.x;
  const float* pv = psv + (size_t)q*NS*KK;
  const int*   pi = psi + (size_t)q*NS*KK;
  int pos[NS]; float hv[NS]; int hi[NS];
  #pragma unroll
  for (int p=0;p<NS;p++){ pos[p]=0; hv[p]=pv[p*KK]; hi[p]=pi[p*KK]; }
  #pragma unroll
  for (int k=0;k<KK;k++){
    int best=0; float bv=hv[0]; int bi=hi[0];
    #pragma unroll
    for (int p=1;p<NS;p++){
      bool g=(hv[p]<bv)||((hv[p]==bv)&&(hi[p]<bi));
      if (g){ bv=hv[p]; bi=hi[p]; best=p; }
    }
    oidx[q*KK+k]=bi;
    #pragma unroll
    for (int p=0;p<NS;p++) if (best==p){
      pos[p]++;
      bool ok = pos[p]<KK;
      hv[p] = ok ? pv[p*KK+pos[p]] : 3.4e38f;
      hi[p] = ok ? pi[p*KK+pos[p]] : 0x7fffffff;
    }
  }
}

// ---------------- rel = p_i - p_knn ; y = rel @ Wp1 ; stats ----------------
__global__ __launch_bounds__(256) void k_rel(const float4* __restrict__ pts4, const int* __restrict__ kidx,
    const float* __restrict__ Wp1, float* __restrict__ y, float* __restrict__ st) {
  int r = blockIdx.x*256 + threadIdx.x;
  int i = r>>4;
  int j = kidx[r];
  float4 pi=pts4[i], pj=pts4[j];
  float rx=pi.x-pj.x, ry=pi.y-pj.y, rz=pi.z-pj.z;
  float s[3], sq[3];
  #pragma unroll
  for (int c=0;c<3;c++){
    float yc = rx*Wp1[c] + ry*Wp1[3+c] + rz*Wp1[6+c];
    y[r*3+c]=yc; s[c]=yc; sq[c]=yc*yc;
  }
  #pragma unroll
  for (int c=0;c<3;c++){
    float a=s[c], b=sq[c];
    #pragma unroll
    for (int o=32;o;o>>=1){ a+=__shfl_down(a,o); b+=__shfl_down(b,o); }
    if ((threadIdx.x&63)==0){ atomicAdd(&st[c],a); atomicAdd(&st[3+c],b); }
  }
}

// ---------------- yn = relu(bn(y)) ----------------
__global__ __launch_bounds__(256) void k_yn(const float* __restrict__ y, const float* __restrict__ st,
    const float* __restrict__ gp, const float* __restrict__ bp, float* __restrict__ yn) {
  int r = blockIdx.x*256 + threadIdx.x;
  const float invn = 1.f/(float)(NP*KK);
  #pragma unroll
  for (int c=0;c<3;c++){
    float m = st[c]*invn;
    float var = st[3+c]*invn - m*m;
    float rs = 1.f/sqrtf(var+1e-5f);
    float t = (y[r*3+c]-m)*rs;
    t = fmaf(t, gp[c], bp[c]);
    yn[r*3+c] = fmaxf(t,0.f);
  }
}

// ---------------- stats of x = fq - fk[knn] + rpe ----------------
__global__ __launch_bounds__(256) void k_xstats(const float* __restrict__ fq, const float* __restrict__ fk,
    const int* __restrict__ kidx, const float* __restrict__ yn, const float* __restrict__ Wp2,
    float* __restrict__ st) {
  __shared__ float red[2][4][64];
  int w=threadIdx.x>>6, c=threadIdx.x&63;
  float w0=Wp2[c], w1=Wp2[64+c], w2=Wp2[128+c];
  float s=0.f,sq=0.f;
  int row0 = blockIdx.x*256 + w*64;
  for (int t=0;t<64;t++){
    int r=row0+t; int p=r>>4; int j=kidx[r];
    float y0=yn[r*3], y1=yn[r*3+1], y2=yn[r*3+2];
    float x = fq[p*CO+c]-fk[j*CO+c]+(y0*w0+y1*w1+y2*w2);
    s+=x; sq=fmaf(x,x,sq);
  }
  red[0][w][c]=s; red[1][w][c]=sq;
  __syncthreads();
  if (w==0){
    float a=red[0][0][c]+red[0][1][c]+red[0][2][c]+red[0][3][c];
    float b=red[1][0][c]+red[1][1][c]+red[1][2][c]+red[1][3][c];
    atomicAdd(&st[c],a); atomicAdd(&st[64+c],b);
  }
}

// ---------------- stats of x1 = relu(bn1(x)) @ Wa1 ----------------
__global__ __launch_bounds__(256) void k_x1stats(const float* __restrict__ fq,const float* __restrict__ fk,
    const int* __restrict__ kidx, const float* __restrict__ yn, const float* __restrict__ Wp2,
    const float* __restrict__ Wa1, const float* __restrict__ ga1, const float* __restrict__ ba1,
    const float* __restrict__ stx, float* __restrict__ st1) {
  __shared__ float wa1[4096];
  __shared__ float red[2][4][64];
  for (int t=threadIdx.x;t<4096;t+=256) wa1[t]=Wa1[t];
  int w=threadIdx.x>>6, c=threadIdx.x&63;
  const float invn=1.f/(float)(NP*KK);
  float m1=stx[c]*invn; float vv=stx[64+c]*invn-m1*m1; float rs1=1.f/sqrtf(vv+1e-5f);
  float g1=ga1[c], bb1=ba1[c];
  float w0=Wp2[c],w1=Wp2[64+c],w2=Wp2[128+c];
  __syncthreads();
  float s=0.f,sq=0.f;
  int row0 = blockIdx.x*128 + w*32;
  for (int t=0;t<32;t++){
    int r=row0+t; int p=r>>4; int j=kidx[r];
    float y0=yn[r*3],y1=yn[r*3+1],y2=yn[r*3+2];
    float x = fq[p*CO+c]-fk[j*CO+c]+(y0*w0+y1*w1+y2*w2);
    float tt=(x-m1)*rs1; tt=fmaxf(fmaf(tt,g1,bb1),0.f);
    float x1 = waveGemm64(tt, wa1, c);
    s += x1; sq = fmaf(x1,x1,sq);
  }
  red[0][w][c]=s; red[1][w][c]=sq;
  __syncthreads();
  if (w==0){
    float a=red[0][0][c]+red[0][1][c]+red[0][2][c]+red[0][3][c];
    float b=red[1][0][c]+red[1][1][c]+red[1][2][c]+red[1][3][c];
    atomicAdd(&st1[c],a); atomicAdd(&st1[64+c],b);
  }
}

// ---------------- attention: x2, softmax over K, skip ----------------
__global__ __launch_bounds__(256) void k_attn(const float* __restrict__ fq,const float* __restrict__ fk,
    const float* __restrict__ fv,const int* __restrict__ kidx,const float* __restrict__ yn,
    const float* __restrict__ Wp2,const float* __restrict__ Wa1,const float* __restrict__ Wa2,
    const float* __restrict__ ga1,const float* __restrict__ ba1,const float* __restrict__ ga2,
    const float* __restrict__ ba2,const float* __restrict__ b_a2,
    const float* __restrict__ stx,const float* __restrict__ st1, float* __restrict__ skip) {
  __shared__ float wa1[4096], wa2[4096];
  __shared__ float sc[4][16][64];
  for (int t=threadIdx.x;t<4096;t+=256){ wa1[t]=Wa1[t]; wa2[t]=Wa2[t]; }
  int w=threadIdx.x>>6, c=threadIdx.x&63;
  int p = blockIdx.x*4 + w;
  const float invn = 1.f/(float)(NP*KK);
  float m1=stx[c]*invn; float va=stx[64+c]*invn-m1*m1; float rs1=1.f/sqrtf(va+1e-5f);
  float m2=st1[c]*invn; float vb=st1[64+c]*invn-m2*m2; float rs2=1.f/sqrtf(vb+1e-5f);
  float g1=ga1[c], bb1=ba1[c], g2=ga2[c], bb2=ba2[c], bc=b_a2[c];
  float w0=Wp2[c], w1=Wp2[64+c], w2=Wp2[128+c];
  float fqv = fq[p*CO+c];
  __syncthreads();
  for (int k=0;k<16;k++){
    int r=p*16+k; int j=kidx[r];
    float y0=yn[r*3],y1=yn[r*3+1],y2=yn[r*3+2];
    float x = fqv - fk[j*CO+c] + (y0*w0+y1*w1+y2*w2);
    float t1 = (x-m1)*rs1; t1 = fmaxf(fmaf(t1,g1,bb1),0.f);
    float x1 = waveGemm64(t1, wa1, c);
    float t2 = (x1-m2)*rs2; t2 = fmaxf(fmaf(t2,g2,bb2),0.f);
    float x2 = waveGemm64(t2, wa2, c) + bc;
    sc[w][k][c] = x2;
  }
  float mx = sc[w][0][c];
  #pragma unroll
  for (int k=1;k<16;k++) mx = fmaxf(mx, sc[w][k][c]);
  float sum=0.f;
  for (int k=0;k<16;k++){ float e=expf(sc[w][k][c]-mx); sc[w][k][c]=e; sum+=e; }
  float acc=0.f;
  for (int k=0;k<16;k++){
    int r=p*16+k; int j=kidx[r];
    float y0=yn[r*3],y1=yn[r*3+1],y2=yn[r*3+2];
    float rpe = y0*w0+y1*w1+y2*w2;
    acc = fmaf(sc[w][k][c], fv[j*CO+c]+rpe, acc);
  }
  skip[p*CO+c] = acc/sum;
}

// ---------------- FPS v8: r1 structure + asm-pinned coordinate registers ----------------
// Single change vs r7: after loading px/py/pz, pin each with an empty inline
// asm "+v" constraint. An asm-defined value cannot be rematerialized by
// re-loading from global, so the RA must keep the 48 coord values in VGPRs
// (cap 256 at this occupancy). Theory: r1/r6/r7's 2.15us/step = 256KB/step
// L2 re-stream from compiler-sunk loads (VGPR_Count stuck at 48 = dm only).
// Mechanism check: VGPR_Count must rise to >=100.
#define FPS_DECL(i) float px##i,py##i,pz##i,dm##i;
#define FPS_LOAD(i) { float4 p = pts4[t*16+i]; px##i=p.x; py##i=p.y; pz##i=p.z; dm##i=1e10f; \
                      asm volatile("" : "+v"(px##i), "+v"(py##i), "+v"(pz##i)); }
#define FPS_UPD(i)  { float dx=px##i-fx, dy=py##i-fy, dz=pz##i-fz; \
                      float q0=dx*dx, q1=dy*dy, q2=dz*dz; \
                      float d=(q0+q1)+q2; \
                      float nd=fminf(dm##i,d); dm##i=nd; \
                      bool g = nd>bv; bv=g?nd:bv; bi=g?(base+i):bi; }
__global__ __launch_bounds__(1024,2) void k_fps(const float4* __restrict__ pts4,
    int* __restrict__ sidx) {
  #pragma clang fp contract(off)
  __shared__ float rbv[16];
  __shared__ int rbi[16];
  int t = threadIdx.x;
  int base = t*16;
  FPS_DECL(0)  FPS_DECL(1)  FPS_DECL(2)  FPS_DECL(3)
  FPS_DECL(4)  FPS_DECL(5)  FPS_DECL(6)  FPS_DECL(7)
  FPS_DECL(8)  FPS_DECL(9)  FPS_DECL(10) FPS_DECL(11)
  FPS_DECL(12) FPS_DECL(13) FPS_DECL(14) FPS_DECL(15)
  FPS_LOAD(0)  FPS_LOAD(1)  FPS_LOAD(2)  FPS_LOAD(3)
  FPS_LOAD(4)  FPS_LOAD(5)  FPS_LOAD(6)  FPS_LOAD(7)
  FPS_LOAD(8)  FPS_LOAD(9)  FPS_LOAD(10) FPS_LOAD(11)
  FPS_LOAD(12) FPS_LOAD(13) FPS_LOAD(14) FPS_LOAD(15)
  int far = 0;
  float4 f0 = pts4[0];
  float fx=f0.x, fy=f0.y, fz=f0.z;
  for (int s=0;s<SP;s++){
    if (t==0) sidx[s]=far;
    float bv=-1.f; int bi=0;
    FPS_UPD(0)  FPS_UPD(1)  FPS_UPD(2)  FPS_UPD(3)
    FPS_UPD(4)  FPS_UPD(5)  FPS_UPD(6)  FPS_UPD(7)
    FPS_UPD(8)  FPS_UPD(9)  FPS_UPD(10) FPS_UPD(11)
    FPS_UPD(12) FPS_UPD(13) FPS_UPD(14) FPS_UPD(15)
    #pragma unroll
    for (int o=1;o<64;o<<=1){
      float ov=__shfl_xor(bv,o); int oi=__shfl_xor(bi,o);
      bool g = (ov>bv)||((ov==bv)&&(oi<bi));
      bv=g?ov:bv; bi=g?oi:bi;
    }
    __syncthreads();
    if ((t&63)==0){ rbv[t>>6]=bv; rbi[t>>6]=bi; }
    __syncthreads();
    float cv=rbv[t&15]; int ci=rbi[t&15];
    #pragma unroll
    for (int o=1;o<16;o<<=1){
      float ov=__shfl_xor(cv,o); int oi=__shfl_xor(ci,o);
      bool g=(ov>cv)||((ov==cv)&&(oi<ci));
      cv=g?ov:cv; ci=g?oi:ci;
    }
    far = ci;
    float4 fp = pts4[far];
    fx=fp.x; fy=fp.y; fz=fp.z;
  }
}

// ---------------- gather sampled points ----------------
__global__ __launch_bounds__(256) void k_gather(const float4* __restrict__ pts4, const int* __restrict__ sidx,
    float4* __restrict__ spts4) {
  int q = blockIdx.x*256 + threadIdx.x;
  spts4[q] = pts4[sidx[q]];
}

// ---------------- TransitionDown pass 1 ----------------
__global__ __launch_bounds__(256) void k_d1(const float* __restrict__ skip, const int* __restrict__ idx2,
    const float* __restrict__ Wd1, float* __restrict__ t1, float* __restrict__ st) {
  __shared__ float wl[4096];
  __shared__ float red[2][4][64];
  for (int t=threadIdx.x;t<4096;t+=256) wl[t]=Wd1[t];
  int w=threadIdx.x>>6, c=threadIdx.x&63;
  __syncthreads();
  float s=0.f,sq=0.f;
  int row0 = blockIdx.x*64 + w*16;
  for (int t=0;t<16;t++){
    int r=row0+t; int src=idx2[r];
    float kf = skip[src*CO+c];
    float o = waveGemm64(kf, wl, c);
    t1[r*CO+c]=o; s+=o; sq=fmaf(o,o,sq);
  }
  red[0][w][c]=s; red[1][w][c]=sq;
  __syncthreads();
  if (w==0){
    float a=red[0][0][c]+red[0][1][c]+red[0][2][c]+red[0][3][c];
    float b=red[1][0][c]+red[1][1][c]+red[1][2][c]+red[1][3][c];
    atomicAdd(&st[c],a); atomicAdd(&st[64+c],b);
  }
}

// ---------------- TransitionDown pass 2 ----------------
__global__ __launch_bounds__(256) void k_d2(const float* __restrict__ t1in, const float* __restrict__ stin,
    const float* __restrict__ gd1, const float* __restrict__ bd1, const float* __restrict__ Wd2,
    float* __restrict__ t2, float* __restrict__ st) {
  __shared__ float wl[4096];
  __shared__ float red[2][4][64];
  for (int t=threadIdx.x;t<4096;t+=256) wl[t]=Wd2[t];
  int w=threadIdx.x>>6, c=threadIdx.x&63;
  const float invn = 1.f/(float)(SP*KK);
  float m=stin[c]*invn; float va=stin[64+c]*invn-m*m; float rs=1.f/sqrtf(va+1e-5f);
  float g=gd1[c], bb=bd1[c];
  __syncthreads();
  float s=0.f,sq=0.f;
  int row0 = blockIdx.x*64 + w*16;
  for (int t=0;t<16;t++){
    int r=row0+t;
    float h = (t1in[r*CO+c]-m)*rs; h = fmaxf(fmaf(h,g,bb),0.f);
    float o = waveGemm64(h, wl, c);
    t2[r*CO+c]=o; s+=o; sq=fmaf(o,o,sq);
  }
  red[0][w][c]=s; red[1][w][c]=sq;
  __syncthreads();
  if (w==0){
    float a=red[0][0][c]+red[0][1][c]+red[0][2][c]+red[0][3][c];
    float b=red[1][0][c]+red[1][1][c]+red[1][2][c]+red[1][3][c];
    atomicAdd(&st[c],a); atomicAdd(&st[64+c],b);
  }
}

// ---------------- down_f = max_k relu(bn(t2)); df = down_f @ Wdn + bdn ----------------
__global__ __launch_bounds__(256) void k_downf(const float* __restrict__ t2, const float* __restrict__ stin,
    const float* __restrict__ gd2, const float* __restrict__ bd2, const float* __restrict__ Wdn,
    const float* __restrict__ bdn, float* __restrict__ df) {
  __shared__ float wl[4096];
  for (int t=threadIdx.x;t<4096;t+=256) wl[t]=Wdn[t];
  int w=threadIdx.x>>6, c=threadIdx.x&63;
  int srow = blockIdx.x*4 + w;
  const float invn = 1.f/(float)(SP*KK);
  float m=stin[c]*invn; float va=stin[64+c]*invn-m*m; float rs=1.f/sqrtf(va+1e-5f);
  float g=gd2[c], bb=bd2[c];
  __syncthreads();
  float mx=-3.4e38f;
  for (int k=0;k<16;k++){
    float h=(t2[(srow*16+k)*CO+c]-m)*rs; h=fmaxf(fmaf(h,g,bb),0.f);
    mx=fmaxf(mx,h);
  }
  float o = waveGemm64(mx, wl, c) + bdn[c];
  df[srow*CO+c]=o;
}

// ---------------- KNN k=3 with distances ----------------
__global__ __launch_bounds__(256,4) void k_knn3(const float4* __restrict__ qp, const float4* __restrict__ cp,
    int* __restrict__ idx3, float* __restrict__ d3) {
  __shared__ float4 tile[2048];
  int q = blockIdx.x*256 + threadIdx.x;
  float4 Q = qp[q];
  float v0=3.4e38f,v1=3.4e38f,v2=3.4e38f;
  int i0=0x7fffffff,i1=0x7fffffff,i2=0x7fffffff;
  for (int base=0;base<SP;base+=2048){
    __syncthreads();
    for (int tt=threadIdx.x;tt<2048;tt+=256) tile[tt]=cp[base+tt];
    __syncthreads();
    for (int j=0;j<2048;j++){
      float4 cpt = tile[j];
      float dot = Q.x*cpt.x + Q.y*cpt.y + Q.z*cpt.z;
      float d = fmaf(-2.f, dot, Q.w) + cpt.w;
      if (d < v2){
        int gj = base+j;
        bool s2 = d < v1;             // shift v1 -> v2 ?
        bool s1 = d < v0;             // shift v0 -> v1 ?
        v2 = s2 ? v1 : d;  i2 = s2 ? i1 : gj;
        v1 = s2 ? (s1 ? v0 : d) : v1; i1 = s2 ? (s1 ? i0 : gj) : i1;
        v0 = s1 ? d : v0;  i0 = s1 ? gj : i0;
      }
    }
  }
  idx3[q*3]=i0; idx3[q*3+1]=i1; idx3[q*3+2]=i2;
  d3[q*3]=v0; d3[q*3+1]=v1; d3[q*3+2]=v2;
}

// ---------------- final: interp + skip @ Wup + bup ----------------
__global__ __launch_bounds__(256) void k_out(const float* __restrict__ df, const int* __restrict__ idx3,
    const float* __restrict__ d3, const float* __restrict__ skip, const float* __restrict__ Wup,
    const float* __restrict__ bup, float* __restrict__ out) {
  __shared__ float wl[4096];
  for (int t=threadIdx.x;t<4096;t+=256) wl[t]=Wup[t];
  int w=threadIdx.x>>6, c=threadIdx.x&63;
  int i = blockIdx.x*4 + w;
  __syncthreads();
  int j0=idx3[i*3], j1=idx3[i*3+1], j2=idx3[i*3+2];
  float e0=d3[i*3], e1=d3[i*3+1], e2=d3[i*3+2];
  float r0=1.f/(e0+1e-8f), r1=1.f/(e1+1e-8f), r2=1.f/(e2+1e-8f);
  float sm=(r0+r1)+r2;
  float w0=r0/sm, w1=r1/sm, w2=r2/sm;
  float interp = (w0*df[j0*CO+c] + w1*df[j1*CO+c]) + w2*df[j2*CO+c];
  float sk = skip[i*CO+c];
  float up = waveGemm64(sk, wl, c);
  out[i*CO+c] = (interp + up) + bup[c];
}

// ---------------- launch ----------------
extern "C" void kernel_launch(void* const* d_in, const int* in_sizes, int n_in,
                              void* d_out, int out_size, void* d_ws, size_t ws_size,
                              hipStream_t stream) {
  (void)in_sizes; (void)n_in; (void)out_size; (void)ws_size;
  const float* points   = (const float*)d_in[0];
  const float* features = (const float*)d_in[1];
  const float* Wq  = (const float*)d_in[2];
  const float* Wk  = (const float*)d_in[3];
  const float* Wv  = (const float*)d_in[4];
  const float* ga1 = (const float*)d_in[5];
  const float* ba1 = (const float*)d_in[6];
  const float* Wa1 = (const float*)d_in[7];
  const float* ga2 = (const float*)d_in[8];
  const float* ba2 = (const float*)d_in[9];
  const float* Wa2 = (const float*)d_in[10];
  const float* b_a2= (const float*)d_in[11];
  const float* Wp1 = (const float*)d_in[12];
  const float* gp  = (const float*)d_in[13];
  const float* bp  = (const float*)d_in[14];
  const float* Wp2 = (const float*)d_in[15];
  const float* Wd1 = (const float*)d_in[16];
  const float* gd1 = (const float*)d_in[17];
  const float* bd1 = (const float*)d_in[18];
  const float* Wd2 = (const float*)d_in[19];
  const float* gd2 = (const float*)d_in[20];
  const float* bd2 = (const float*)d_in[21];
  const float* Wup = (const float*)d_in[22];
  const float* bup = (const float*)d_in[23];
  const float* Wdn = (const float*)d_in[24];
  const float* bdn = (const float*)d_in[25];
  float* out = (float*)d_out;

  char* wp = (char*)d_ws;
  auto carve = [&](size_t bytes)->char* { char* p = wp; wp += (bytes + 255) & ~(size_t)255; return p; };
  float4* pts4  = (float4*)carve((size_t)NP*16);
  float*  fq    = (float*) carve((size_t)NP*CO*4);
  float*  fk    = (float*) carve((size_t)NP*CO*4);
  float*  fv    = (float*) carve((size_t)NP*CO*4);
  int*    kidx  = (int*)   carve((size_t)NP*KK*4);
  float*  y     = (float*) carve((size_t)NP*KK*3*4);
  float*  yn    = (float*) carve((size_t)NP*KK*3*4);
  float*  skip  = (float*) carve((size_t)NP*CO*4);
  int*    sidx  = (int*)   carve((size_t)SP*4);
  float4* spts4 = (float4*)carve((size_t)SP*16);
  int*    idx2  = (int*)   carve((size_t)SP*KK*4);
  float*  t1    = (float*) carve((size_t)SP*KK*CO*4);   // 16MB; split bufs alias head
  float*  t2    = (float*) carve((size_t)SP*KK*CO*4);   // 16MB
  float*  df    = (float*) carve((size_t)SP*CO*4);
  int*    idx3  = (int*)   carve((size_t)NP*3*4);
  float*  d3    = (float*) carve((size_t)NP*3*4);
  float*  stats = (float*) carve(4096);                 // zeroed each launch
  float* stRel = stats;        // 6 floats
  float* stX   = stats + 8;    // 128
  float* stX1  = stats + 136;  // 128
  float* stD1  = stats + 264;  // 128
  float* stD2  = stats + 392;  // 128
  // KNN split buffers alias t1/t2 (consumed by merges before k_d1/k_d2 write them)
  float* psvNP = t1;                         // 16384*4*16*4B = 4MB
  int*   psiNP = (int*)(t1 + (size_t)NP*4*KK);
  float* psvSP = t2;                         // 4096*8*16*4B = 2MB
  int*   psiSP = (int*)(t2 + (size_t)SP*8*KK);

  hipMemsetAsync(stats, 0, 4096, stream);

  k_pts4   <<<NP/256, 256, 0, stream>>>(points, pts4);
  // transformer layer
  k_qkv    <<<NP/4,   256, 0, stream>>>(features, Wq, Wk, Wv, fq, fk, fv);
  k_knn16p <<<dim3(NP/256,4), 256, 0, stream>>>(pts4, pts4, NP/4, psvNP, psiNP);
  k_merge<4><<<NP/256, 256, 0, stream>>>(psvNP, psiNP, kidx);
  k_rel    <<<NP*KK/256, 256, 0, stream>>>(pts4, kidx, Wp1, y, stRel);
  k_yn     <<<NP*KK/256, 256, 0, stream>>>(y, stRel, gp, bp, yn);
  k_xstats <<<NP*KK/256, 256, 0, stream>>>(fq, fk, kidx, yn, Wp2, stX);
  k_x1stats<<<NP*KK/128, 256, 0, stream>>>(fq, fk, kidx, yn, Wp2, Wa1, ga1, ba1, stX, stX1);
  k_attn   <<<NP/4,   256, 0, stream>>>(fq, fk, fv, kidx, yn, Wp2, Wa1, Wa2, ga1, ba1, ga2, ba2, b_a2, stX, stX1, skip);
  // down / up
  k_fps    <<<1,     1024, 0, stream>>>(pts4, sidx);
  k_gather <<<SP/256, 256, 0, stream>>>(pts4, sidx, spts4);
  k_knn16p <<<dim3(SP/256,8), 256, 0, stream>>>(spts4, pts4, NP/8, psvSP, psiSP);
  k_merge<8><<<SP/256, 256, 0, stream>>>(psvSP, psiSP, idx2);
  k_d1     <<<SP*KK/64, 256, 0, stream>>>(skip, idx2, Wd1, t1, stD1);
  k_d2     <<<SP*KK/64, 256, 0, stream>>>(t1, stD1, gd1, bd1, Wd2, t2, stD2);
  k_downf  <<<SP/4,   256, 0, stream>>>(t2, stD2, gd2, bd2, Wdn, bdn, df);
  k_knn3   <<<NP/256, 256, 0, stream>>>(pts4, spts4, idx3, d3);
  k_out    <<<NP/4,   256, 0, stream>>>(df, idx3, d3, skip, Wup, bup, out);
}